// Round 11
// baseline (209.806 us; speedup 1.0000x reference)
//
#include <hip/hip_runtime.h>
#include <hip/hip_bf16.h>
#include <math.h>

#define ICH   3
#define OCH   16
#define ID    18
#define IH    34
#define IW    34
#define OD    16
#define OH    32
#define OW    32
#define NB    128
#define DCHUNK   4
#define SPATIAL  (OD * OH * OW)     // 16384 per (b,c)
#define EPSV     1e-5f

__device__ __forceinline__ unsigned short f2bf(float f) {
    unsigned int u = __float_as_uint(f);
    unsigned int r = (u + 0x7fffu + ((u >> 16) & 1u)) >> 16;
    return (unsigned short)r;
}

// ===== Fused conv+stats+norm+max, ONE dispatch, manual per-b barrier.
// 512 blocks x 256 threads; block = (b, 4 d-slices). Co-residency proof:
// __launch_bounds__(256,2) caps VGPR at 256 -> >= 2 blocks/CU capacity ->
// >= 512 co-resident blocks >= grid, so the arrival-spin cannot deadlock.
// Phase 1: R9's direct-from-global conv (no LDS staging - proven), write y
// (bf16, channel-major) to global, block-reduce stats, device atomicAdd.
// Barrier: per-b arrival counter (4 blocks/b), device-scope, s_sleep spin.
// Phase 2: each block re-reads ONLY ITS OWN y chunk (L2/L3-warm),
// normalize/clamp/mult/channel-max, write 8 MB out.
// Deletes R9's second 2048-block dispatch + cold-HBM y read.
// Do NOT: raise min-waves (R2/R3 spill), LDS-stage x (R1-R8), keep y in
// registers across the barrier (R10: dynamic-index spill + coop-launch fail).
__global__ __launch_bounds__(256, 2) void fused_kernel(
    const float* __restrict__ x, const float* __restrict__ cw,
    const float* __restrict__ cb, const float* __restrict__ mult,
    unsigned short* __restrict__ y, float* __restrict__ stats,
    int* __restrict__ arrive, float* __restrict__ out)
{
    __shared__ float wsum[4][OCH], wsq[4][OCH];
    __shared__ float srs_s[OCH], snb_s[OCH], smul_s[OCH];

    const int blk = blockIdx.x;
    const int b  = blk >> 2;
    const int d0 = (blk & 3) * DCHUNK;
    const int tid = threadIdx.x;

    const int h  = tid >> 3;        // 0..31
    const int wq = (tid & 7) << 2;  // 0,4,...,28

    float ssum[OCH], ssq[OCH];
#pragma unroll
    for (int c = 0; c < OCH; c++) { ssum[c] = 0.0f; ssq[c] = 0.0f; }

    // ---------------- phase 1: conv + y store + stats ----------------
    for (int dz = 0; dz < DCHUNK; dz++) {
        float acc[OCH][4];
#pragma unroll
        for (int c = 0; c < OCH; c++) {
            const float bv = cb[c];
            acc[c][0] = bv; acc[c][1] = bv; acc[c][2] = bv; acc[c][3] = bv;
        }

        for (int ic = 0; ic < ICH; ic++) {
            for (int kd = 0; kd < 3; kd++) {
                const float* plane =
                    x + ((size_t)(b * ICH + ic) * ID + (d0 + dz + kd)) * (IH * IW);
#pragma unroll
                for (int kh = 0; kh < 3; kh++) {
                    const float* row = plane + (size_t)(h + kh) * IW + wq;
                    const float4 v0 = *(const float4*)row;
                    const float2 v1 = *(const float2*)(row + 4);
                    float in[6];
                    in[0] = v0.x; in[1] = v0.y; in[2] = v0.z; in[3] = v0.w;
                    in[4] = v1.x; in[5] = v1.y;
                    const float* wrow = &cw[(size_t)(ic * 3 + kd) * 9 + kh * 3];
#pragma unroll
                    for (int kw = 0; kw < 3; kw++) {
#pragma unroll
                        for (int c = 0; c < OCH; c++) {
                            const float wv = wrow[(size_t)c * (ICH * 27) + kw];  // s_load
                            acc[c][0] = fmaf(in[kw + 0], wv, acc[c][0]);
                            acc[c][1] = fmaf(in[kw + 1], wv, acc[c][1]);
                            acc[c][2] = fmaf(in[kw + 2], wv, acc[c][2]);
                            acc[c][3] = fmaf(in[kw + 3], wv, acc[c][3]);
                        }
                    }
                }
            }
        }

        const int d = d0 + dz;
#pragma unroll
        for (int c = 0; c < OCH; c++) {
            const float m = mult[c];
            const float o0 = acc[c][0] * m, o1 = acc[c][1] * m;
            const float o2 = acc[c][2] * m, o3 = acc[c][3] * m;
            ssum[c] += (o0 + o1) + (o2 + o3);
            ssq[c]  += (o0 * o0 + o1 * o1) + (o2 * o2 + o3 * o3);
            const size_t yi = ((size_t)(b * OCH + c) * OD + d) * (OH * OW) + h * OW + wq;
            ushort4 pk;
            pk.x = f2bf(o0); pk.y = f2bf(o1); pk.z = f2bf(o2); pk.w = f2bf(o3);
            *(ushort4*)&y[yi] = pk;
        }
    }

    // block-reduce stats -> one atomicAdd per (b,c)
#pragma unroll
    for (int c = 0; c < OCH; c++) {
        for (int off = 32; off > 0; off >>= 1) {
            ssum[c] += __shfl_down(ssum[c], off);
            ssq[c]  += __shfl_down(ssq[c], off);
        }
    }
    const int wave = tid >> 6, lane = tid & 63;
    if (lane == 0) {
#pragma unroll
        for (int c = 0; c < OCH; c++) { wsum[wave][c] = ssum[c]; wsq[wave][c] = ssq[c]; }
    }
    __syncthreads();
    if (tid < OCH) {
        float s = 0.0f, q = 0.0f;
#pragma unroll
        for (int k = 0; k < 4; k++) { s += wsum[k][tid]; q += wsq[k][tid]; }
        atomicAdd(&stats[(b * OCH + tid) * 2 + 0], s);
        atomicAdd(&stats[(b * OCH + tid) * 2 + 1], q);
    }

    // ---------------- per-b barrier (4 blocks) ----------------
    __syncthreads();                 // drains vmcnt -> stats atomics complete
    if (tid == 0) {
        __threadfence();             // release stats
        __hip_atomic_fetch_add(&arrive[b], 1, __ATOMIC_RELEASE,
                               __HIP_MEMORY_SCOPE_AGENT);
        while (__hip_atomic_load(&arrive[b], __ATOMIC_ACQUIRE,
                                 __HIP_MEMORY_SCOPE_AGENT) < 4) {
            __builtin_amdgcn_s_sleep(8);
        }
        __threadfence();             // acquire stats
    }
    __syncthreads();

    // ---------------- phase 2: normalize + clamp + mult + channel-max ----------------
    if (tid < OCH) {
        const float s  = stats[(b * OCH + tid) * 2 + 0];
        const float sq = stats[(b * OCH + tid) * 2 + 1];
        const float mean = s * (1.0f / (float)SPATIAL);
        float var = sq * (1.0f / (float)SPATIAL) - mean * mean;
        var = fmaxf(var, 0.0f);
        const float rs = rsqrtf(var + EPSV);
        srs_s[tid]  = rs;
        snb_s[tid]  = -mean * rs;      // normalized = v*rs + nb
        smul_s[tid] = mult[tid];
    }
    __syncthreads();

    float rs[OCH], nb[OCH], mm[OCH];
#pragma unroll
    for (int c = 0; c < OCH; c++) { rs[c] = srs_s[c]; nb[c] = snb_s[c]; mm[c] = smul_s[c]; }

    for (int dz = 0; dz < DCHUNK; dz++) {
        const int d = d0 + dz;
        const int s = d * (OH * OW) + h * OW + wq;
        const unsigned short* yb = y + (size_t)b * OCH * SPATIAL + s;

        uint2 v[OCH];
#pragma unroll
        for (int c = 0; c < OCH; c++) {
            v[c] = *(const uint2*)(yb + (size_t)c * SPATIAL);   // L2/L3-warm (own writes)
        }

        float b0 = -INFINITY, b1 = -INFINITY, b2 = -INFINITY, b3 = -INFINITY;
#pragma unroll
        for (int c = 0; c < OCH; c++) {
            float f0 = __uint_as_float(v[c].x << 16)         * rs[c] + nb[c];
            float f1 = __uint_as_float(v[c].x & 0xffff0000u) * rs[c] + nb[c];
            float f2 = __uint_as_float(v[c].y << 16)         * rs[c] + nb[c];
            float f3 = __uint_as_float(v[c].y & 0xffff0000u) * rs[c] + nb[c];
            f0 = fminf(fmaxf(f0, -1.0f), 1.0f) * mm[c];
            f1 = fminf(fmaxf(f1, -1.0f), 1.0f) * mm[c];
            f2 = fminf(fmaxf(f2, -1.0f), 1.0f) * mm[c];
            f3 = fminf(fmaxf(f3, -1.0f), 1.0f) * mm[c];
            b0 = fmaxf(b0, f0); b1 = fmaxf(b1, f1);
            b2 = fmaxf(b2, f2); b3 = fmaxf(b3, f3);
        }
        float4 o; o.x = b0; o.y = b1; o.z = b2; o.w = b3;
        *(float4*)&out[(size_t)b * SPATIAL + s] = o;
    }
}

extern "C" void kernel_launch(void* const* d_in, const int* in_sizes, int n_in,
                              void* d_out, int out_size, void* d_ws, size_t ws_size,
                              hipStream_t stream) {
    const float* x    = (const float*)d_in[0];
    const float* cw   = (const float*)d_in[1];
    const float* cb   = (const float*)d_in[2];
    const float* mult = (const float*)d_in[3];
    float* out = (float*)d_out;

    // ws layout: y (64 MB bf16) | stats (128*16*2 f32) | arrive (128 int)
    unsigned short* y = (unsigned short*)d_ws;
    float* stats = (float*)((char*)d_ws + (size_t)NB * OCH * SPATIAL * sizeof(unsigned short));
    int* arrive  = (int*)(stats + NB * OCH * 2);

    hipMemsetAsync(stats, 0, NB * OCH * 2 * sizeof(float) + NB * sizeof(int), stream);
    fused_kernel<<<NB * 4, 256, 0, stream>>>(x, cw, cb, mult, y, stats, arrive, out);
}

// Round 12
// 154.798 us; speedup vs baseline: 1.3554x; 1.3554x over previous
//
#include <hip/hip_runtime.h>
#include <hip/hip_bf16.h>
#include <math.h>

#define ICH   3
#define OCH   16
#define ID    18
#define IH    34
#define IW    34
#define OD    16
#define OH    32
#define OW    32
#define NB    128
#define SPATIAL  (OD * OH * OW)     // 16384 per (b,c)
#define EPSV     1e-5f

__device__ __forceinline__ unsigned short f2bf(float f) {
    unsigned int u = __float_as_uint(f);
    unsigned int r = (u + 0x7fffu + ((u >> 16) & 1u)) >> 16;
    return (unsigned short)r;
}

// ===== conv v5: R9's direct-from-global loop, one d-slice per block.
// Grid 2048 (8 blocks/CU submitted, ~7 resident at VGPR~68 -> ~28 waves/CU,
// 2x R9's latency hiding). Insight from R9's asm-level view: the dz loop
// re-loaded all rows from cache anyway (L1 reuse, not register reuse), so
// DCHUNK=1 costs no extra loads per output - it only adds blocks.
// Keep: no LDS staging (R9's +16us win), uniform weight idx -> s_load,
// 4 w/thread, (256,2) bounds.
// Do NOT: raise min-waves (R2/R3 spill), LDS-stage x (R1-R8), fuse with a
// grid cap (R11: 512 blocks -> VALUBusy 37%), fp16 staging (R5).
__global__ __launch_bounds__(256, 2) void conv_stats_kernel(
    const float* __restrict__ x, const float* __restrict__ cw,
    const float* __restrict__ cb, const float* __restrict__ mult,
    unsigned short* __restrict__ y, float* __restrict__ stats)
{
    __shared__ float wsum[4][OCH], wsq[4][OCH];

    const int blk = blockIdx.x;
    const int b = blk >> 4;
    const int d = blk & 15;
    const int tid = threadIdx.x;

    const int h  = tid >> 3;        // 0..31
    const int wq = (tid & 7) << 2;  // 0,4,...,28

    float acc[OCH][4];
#pragma unroll
    for (int c = 0; c < OCH; c++) {
        const float bv = cb[c];
        acc[c][0] = bv; acc[c][1] = bv; acc[c][2] = bv; acc[c][3] = bv;
    }

    for (int ic = 0; ic < ICH; ic++) {
        for (int kd = 0; kd < 3; kd++) {
            const float* plane = x + ((size_t)(b * ICH + ic) * ID + (d + kd)) * (IH * IW);
#pragma unroll
            for (int kh = 0; kh < 3; kh++) {
                const float* row = plane + (size_t)(h + kh) * IW + wq;
                const float4 v0 = *(const float4*)row;
                const float2 v1 = *(const float2*)(row + 4);
                float in[6];
                in[0] = v0.x; in[1] = v0.y; in[2] = v0.z; in[3] = v0.w;
                in[4] = v1.x; in[5] = v1.y;
                const float* wrow = &cw[(size_t)(ic * 3 + kd) * 9 + kh * 3];
#pragma unroll
                for (int kw = 0; kw < 3; kw++) {
#pragma unroll
                    for (int c = 0; c < OCH; c++) {
                        const float wv = wrow[(size_t)c * (ICH * 27) + kw];  // s_load
                        acc[c][0] = fmaf(in[kw + 0], wv, acc[c][0]);
                        acc[c][1] = fmaf(in[kw + 1], wv, acc[c][1]);
                        acc[c][2] = fmaf(in[kw + 2], wv, acc[c][2]);
                        acc[c][3] = fmaf(in[kw + 3], wv, acc[c][3]);
                    }
                }
            }
        }
    }

    // ---- multiplier fold, stats, bf16 store ----
    float ssum[OCH], ssq[OCH];
#pragma unroll
    for (int c = 0; c < OCH; c++) {
        const float m = mult[c];
        const float o0 = acc[c][0] * m, o1 = acc[c][1] * m;
        const float o2 = acc[c][2] * m, o3 = acc[c][3] * m;
        ssum[c] = (o0 + o1) + (o2 + o3);
        ssq[c]  = (o0 * o0 + o1 * o1) + (o2 * o2 + o3 * o3);
        const size_t yi = ((size_t)(b * OCH + c) * OD + d) * (OH * OW) + h * OW + wq;
        ushort4 pk;
        pk.x = f2bf(o0); pk.y = f2bf(o1); pk.z = f2bf(o2); pk.w = f2bf(o3);
        *(ushort4*)&y[yi] = pk;
    }

    // ---- block reduction of stats, one atomicAdd per (b,c) ----
#pragma unroll
    for (int c = 0; c < OCH; c++) {
        for (int off = 32; off > 0; off >>= 1) {
            ssum[c] += __shfl_down(ssum[c], off);
            ssq[c]  += __shfl_down(ssq[c], off);
        }
    }
    const int wave = tid >> 6, lane = tid & 63;
    if (lane == 0) {
#pragma unroll
        for (int c = 0; c < OCH; c++) { wsum[wave][c] = ssum[c]; wsq[wave][c] = ssq[c]; }
    }
    __syncthreads();
    if (tid < OCH) {
        float s = 0.0f, q = 0.0f;
#pragma unroll
        for (int k = 0; k < 4; k++) { s += wsum[k][tid]; q += wsq[k][tid]; }
        atomicAdd(&stats[(b * OCH + tid) * 2 + 0], s);
        atomicAdd(&stats[(b * OCH + tid) * 2 + 1], q);
    }
}

// ===== norm_max (R9 config — real cost ~17 us once harness overhead is
// accounted; leave alone). 2048 blocks, 4 positions/thread, loads hoisted.
__global__ __launch_bounds__(256, 2) void norm_max_kernel(
    const unsigned short* __restrict__ y, const float* __restrict__ stats,
    const float* __restrict__ mult, float* __restrict__ out)
{
    const int blk = blockIdx.x;
    const int b   = blk >> 4;
    const int seg = blk & 15;
    const int tid = threadIdx.x;

    __shared__ float srs_s[OCH], snb_s[OCH], smul_s[OCH];
    if (tid < OCH) {
        const float s  = stats[(b * OCH + tid) * 2 + 0];
        const float sq = stats[(b * OCH + tid) * 2 + 1];
        const float mean = s * (1.0f / (float)SPATIAL);
        float var = sq * (1.0f / (float)SPATIAL) - mean * mean;
        var = fmaxf(var, 0.0f);
        const float rs = rsqrtf(var + EPSV);
        srs_s[tid]  = rs;
        snb_s[tid]  = -mean * rs;      // normalized = v*rs + nb
        smul_s[tid] = mult[tid];
    }
    __syncthreads();

    const int s = seg * 1024 + tid * 4;
    const unsigned short* yb = y + (size_t)b * OCH * SPATIAL + s;

    uint2 v[OCH];
#pragma unroll
    for (int c = 0; c < OCH; c++) {
        v[c] = *(const uint2*)(yb + (size_t)c * SPATIAL);
    }

    float rs[OCH], nb[OCH], mm[OCH];
#pragma unroll
    for (int c = 0; c < OCH; c++) { rs[c] = srs_s[c]; nb[c] = snb_s[c]; mm[c] = smul_s[c]; }

    float b0 = -INFINITY, b1 = -INFINITY, b2 = -INFINITY, b3 = -INFINITY;
#pragma unroll
    for (int c = 0; c < OCH; c++) {
        float f0 = __uint_as_float(v[c].x << 16)         * rs[c] + nb[c];
        float f1 = __uint_as_float(v[c].x & 0xffff0000u) * rs[c] + nb[c];
        float f2 = __uint_as_float(v[c].y << 16)         * rs[c] + nb[c];
        float f3 = __uint_as_float(v[c].y & 0xffff0000u) * rs[c] + nb[c];
        f0 = fminf(fmaxf(f0, -1.0f), 1.0f) * mm[c];
        f1 = fminf(fmaxf(f1, -1.0f), 1.0f) * mm[c];
        f2 = fminf(fmaxf(f2, -1.0f), 1.0f) * mm[c];
        f3 = fminf(fmaxf(f3, -1.0f), 1.0f) * mm[c];
        b0 = fmaxf(b0, f0); b1 = fmaxf(b1, f1);
        b2 = fmaxf(b2, f2); b3 = fmaxf(b3, f3);
    }
    float4 o; o.x = b0; o.y = b1; o.z = b2; o.w = b3;
    *(float4*)&out[(size_t)b * SPATIAL + s] = o;
}

extern "C" void kernel_launch(void* const* d_in, const int* in_sizes, int n_in,
                              void* d_out, int out_size, void* d_ws, size_t ws_size,
                              hipStream_t stream) {
    const float* x    = (const float*)d_in[0];
    const float* cw   = (const float*)d_in[1];
    const float* cb   = (const float*)d_in[2];
    const float* mult = (const float*)d_in[3];
    float* out = (float*)d_out;

    unsigned short* y = (unsigned short*)d_ws;   // channel-major, 64 MB
    float* stats = (float*)((char*)d_ws + (size_t)NB * OCH * SPATIAL * sizeof(unsigned short));

    hipMemsetAsync(stats, 0, (size_t)NB * OCH * 2 * sizeof(float), stream);
    conv_stats_kernel<<<NB * 16, 256, 0, stream>>>(x, cw, cb, mult, y, stats);
    norm_max_kernel<<<NB * 16, 256, 0, stream>>>(y, stats, mult, out);
}